// Round 9
// baseline (619.904 us; speedup 1.0000x reference)
//
#include <hip/hip_runtime.h>
#include <cstdint>
#include <cstddef>

#define NN 100000
#define NE 1600000
#define NTOT (NE + NN)      // 1700000 edges incl self-loops
#define HF 128
#define OF 64
#define SHARD 12500         // NN/8 dst-range per XCD
#define EPB 1924            // edges per chunk: 832*1924 >= NE
#define NPB 16              // shard nodes per chunk: 832*16 >= SHARD

typedef short bfrag_t __attribute__((ext_vector_type(8)));   // 8 bf16 = 4 VGPR
typedef float f4v     __attribute__((ext_vector_type(4)));   // MFMA acc

// ---------------- helpers ----------------

__device__ __forceinline__ unsigned int f2bf_rne(float f) {
    unsigned int u = __float_as_uint(f);
    return (u + 0x7fffu + ((u >> 16) & 1u)) >> 16;
}
__device__ __forceinline__ unsigned int pack_bf2(float lo, float hi) {
    return f2bf_rne(lo) | (f2bf_rne(hi) << 16);
}

// ---------------- graph preprocessing ----------------

__global__ __launch_bounds__(256) void k_init(int* flag, int* deg) {
    int i = blockIdx.x * 256 + threadIdx.x;
    if (i == 0) *flag = 0;
    if (i < NN) deg[i] = 1;   // self-loop
}

// OR-reduce odd 32-bit words of edge_index: all zero <=> data is int64.
__global__ __launch_bounds__(256) void k_detect(const int* ei, int* flag) {
    int t = blockIdx.x * blockDim.x + threadIdx.x;
    int v = 0;
    for (int i = t; i < NE; i += gridDim.x * blockDim.x) v |= ei[2 * i + 1];
    unsigned long long b = __ballot(v != 0);
    if ((threadIdx.x & 63) == 0 && b) atomicOr(flag, 1);
}

__device__ __forceinline__ int edge_src(const int* ei, int e, bool is64) {
    return is64 ? ei[2 * e] : ei[e];
}
__device__ __forceinline__ int edge_dst(const int* ei, int e, bool is64) {
    return is64 ? ei[2 * (NE + e)] : ei[NE + e];
}

// histogram + per-edge rank (rank 0 reserved for the self-loop via deg init=1)
__global__ __launch_bounds__(256) void k_histr(const int* ei, const int* flag,
                                               int* deg, int* rank) {
    int e = blockIdx.x * 256 + threadIdx.x;
    if (e >= NE) return;
    bool is64 = (*flag) == 0;
    rank[e] = atomicAdd(&deg[edge_dst(ei, e, is64)], 1);
}

// exclusive scan of deg[N] -> rowptr (partial), also dinv = rsqrt(deg)
__global__ __launch_bounds__(256) void k_scanA(const int* deg, int* rowptr, int* bsum,
                                               float* dinv) {
    __shared__ int sh[256];
    int tid = threadIdx.x;
    int base = blockIdx.x * 1024 + tid * 4;
    int v0 = 0, v1 = 0, v2 = 0, v3 = 0;
    if (base + 0 < NN) v0 = deg[base + 0];
    if (base + 1 < NN) v1 = deg[base + 1];
    if (base + 2 < NN) v2 = deg[base + 2];
    if (base + 3 < NN) v3 = deg[base + 3];
    if (base + 0 < NN) dinv[base + 0] = rsqrtf((float)v0);
    if (base + 1 < NN) dinv[base + 1] = rsqrtf((float)v1);
    if (base + 2 < NN) dinv[base + 2] = rsqrtf((float)v2);
    if (base + 3 < NN) dinv[base + 3] = rsqrtf((float)v3);
    int s = v0 + v1 + v2 + v3;
    sh[tid] = s;
    __syncthreads();
    for (int off = 1; off < 256; off <<= 1) {
        int t = (tid >= off) ? sh[tid - off] : 0;
        __syncthreads();
        sh[tid] += t;
        __syncthreads();
    }
    int run = sh[tid] - s;
    if (base + 0 < NN) rowptr[base + 0] = run; run += v0;
    if (base + 1 < NN) rowptr[base + 1] = run; run += v1;
    if (base + 2 < NN) rowptr[base + 2] = run; run += v2;
    if (base + 3 < NN) rowptr[base + 3] = run;
    if (tid == 255) bsum[blockIdx.x] = sh[255];
}

__global__ __launch_bounds__(128) void k_scanB(const int* bsum, int* boff, int* rowptr) {
    __shared__ int sh[128];
    int tid = threadIdx.x;
    int v = (tid < 98) ? bsum[tid] : 0;
    sh[tid] = v;
    __syncthreads();
    for (int off = 1; off < 128; off <<= 1) {
        int t = (tid >= off) ? sh[tid - off] : 0;
        __syncthreads();
        sh[tid] += t;
        __syncthreads();
    }
    if (tid < 98) boff[tid] = sh[tid] - v;
    if (tid == 0) rowptr[NN] = NTOT;
}

__global__ __launch_bounds__(256) void k_scanC(int* rowptr, const int* boff) {
    int i = blockIdx.x * 256 + threadIdx.x;
    if (i < NN) rowptr[i] += boff[i >> 10];
}

// XCD-sharded, atomic-free CSR fill (round-robin blockIdx->XCD dst shards).
__global__ __launch_bounds__(256) void k_scat2(const int* __restrict__ ei,
                                               const int* __restrict__ flag,
                                               const int* __restrict__ rank,
                                               const int* __restrict__ rowptr,
                                               int* __restrict__ csr) {
    int x = blockIdx.x & 7, c = blockIdx.x >> 3;
    bool is64 = (*flag) == 0;
    int d0 = x * SHARD;
    int nbeg = d0 + c * NPB;
    int nend = min(d0 + SHARD, nbeg + NPB);
    for (int nd = nbeg + (int)threadIdx.x; nd < nend; nd += 256)
        csr[rowptr[nd]] = nd;
    int ebeg = c * EPB;
    int eend = min(NE, ebeg + EPB);
    for (int e = ebeg + (int)threadIdx.x; e < eend; e += 256) {
        int d = edge_dst(ei, e, is64);
        if ((unsigned)(d - d0) < SHARD) {
            int s = edge_src(ei, e, is64);
            csr[rowptr[d] + rank[e]] = s;
        }
    }
}

// ---------------- weight prep: bf16 + transpose to [n][k] ----------------
__global__ __launch_bounds__(256) void k_prep(const float* __restrict__ W0,
                                              const float* __restrict__ W1,
                                              const float* __restrict__ W2,
                                              const float* __restrict__ W3,
                                              const float* __restrict__ linW,
                                              unsigned short* __restrict__ WT,
                                              unsigned short* __restrict__ WjT) {
    int idx = blockIdx.x * 256 + threadIdx.x;
    if (idx < 4 * 128 * 128) {
        int l = idx >> 14, r = idx & 16383, n = r >> 7, k = r & 127;
        const float* Wl = (l == 0) ? W0 : (l == 1) ? W1 : (l == 2) ? W2 : W3;
        WT[idx] = (unsigned short)f2bf_rne(Wl[k * 128 + n]);
    } else if (idx < 4 * 128 * 128 + 4 * 64 * 128) {
        int i2 = idx - 65536;
        int l = i2 >> 13, r = i2 & 8191, n = r >> 7, k = r & 127;
        WjT[i2] = (unsigned short)f2bf_rne(linW[(size_t)(l * 128 + k) * 64 + n]);
    }
}

// ---------------- MFMA matmul + fused JK ----------------
__global__ __launch_bounds__(256) void k_mmf(const float* __restrict__ A,
                                             const unsigned short* __restrict__ WT,
                                             const float* __restrict__ dinv,
                                             const unsigned short* __restrict__ WjT,
                                             const float* __restrict__ linb,
                                             float* __restrict__ logits, int first,
                                             unsigned short* __restrict__ m16) {
    __shared__ unsigned short Alds[64 * 128];    // 16 KB
    __shared__ unsigned short Wlds[128 * 128];   // 32 KB
    __shared__ unsigned short Wjlds[64 * 128];   // 16 KB
    int tid = threadIdx.x;
    int row0 = blockIdx.x * 64;
    bool has_jk = (WjT != nullptr);

    for (int c = tid; c < 2048; c += 256) {       // W^T, swizzled
        int row = c >> 4, c16 = c & 15;
        uint4 v = *(const uint4*)&WT[row * 128 + c16 * 8];
        *(uint4*)((char*)Wlds + row * 256 + ((c16 * 16) ^ ((row & 7) << 4))) = v;
    }
    if (has_jk) {
        for (int c = tid; c < 1024; c += 256) {
            int row = c >> 4, c16 = c & 15;
            uint4 v = *(const uint4*)&WjT[row * 128 + c16 * 8];
            *(uint4*)((char*)Wjlds + row * 256 + ((c16 * 16) ^ ((row & 7) << 4))) = v;
        }
    }
    {
        int row = tid >> 2, gr = row0 + row;      // A f32->bf16, swizzled
#pragma unroll
        for (int j = 0; j < 4; ++j) {
            int c8 = (tid & 3) * 4 + j;
            float4 v0 = make_float4(0.f, 0.f, 0.f, 0.f);
            float4 v1 = make_float4(0.f, 0.f, 0.f, 0.f);
            if (gr < NN) {
                v0 = *(const float4*)&A[(size_t)gr * 128 + c8 * 8];
                v1 = *(const float4*)&A[(size_t)gr * 128 + c8 * 8 + 4];
            }
            uint4 o;
            o.x = pack_bf2(v0.x, v0.y);
            o.y = pack_bf2(v0.z, v0.w);
            o.z = pack_bf2(v1.x, v1.y);
            o.w = pack_bf2(v1.z, v1.w);
            *(uint4*)((char*)Alds + row * 256 + ((c8 * 16) ^ ((row & 7) << 4))) = o;
        }
    }
    __syncthreads();

    int lane = tid & 63, w = tid >> 6;
    int r15 = lane & 15, q = lane >> 4;
    int xo = (r15 & 7) << 4;

    f4v acc[8], accj[4];
#pragma unroll
    for (int i = 0; i < 8; ++i) acc[i] = (f4v){0.f, 0.f, 0.f, 0.f};
#pragma unroll
    for (int i = 0; i < 4; ++i) accj[i] = (f4v){0.f, 0.f, 0.f, 0.f};

#pragma unroll
    for (int ks = 0; ks < 4; ++ks) {
        int ko = ks * 64 + q * 16;
        bfrag_t a = *(const bfrag_t*)((const char*)Alds + (16 * w + r15) * 256 + (ko ^ xo));
#pragma unroll
        for (int nb = 0; nb < 8; ++nb) {
            bfrag_t b = *(const bfrag_t*)((const char*)Wlds + (nb * 16 + r15) * 256 + (ko ^ xo));
            acc[nb] = __builtin_amdgcn_mfma_f32_16x16x32_bf16(a, b, acc[nb], 0, 0, 0);
        }
        if (has_jk) {
#pragma unroll
            for (int jb = 0; jb < 4; ++jb) {
                bfrag_t b = *(const bfrag_t*)((const char*)Wjlds + (jb * 16 + r15) * 256 + (ko ^ xo));
                accj[jb] = __builtin_amdgcn_mfma_f32_16x16x32_bf16(a, b, accj[jb], 0, 0, 0);
            }
        }
    }

#pragma unroll
    for (int reg = 0; reg < 4; ++reg) {
        int gr = row0 + 16 * w + q * 4 + reg;
        if (gr < NN) {
            float sc = dinv[gr];
#pragma unroll
            for (int nb = 0; nb < 8; ++nb)
                m16[(size_t)gr * 128 + nb * 16 + r15] =
                    (unsigned short)f2bf_rne(acc[nb][reg] * sc);
            if (has_jk) {
#pragma unroll
                for (int jb = 0; jb < 4; ++jb) {
                    size_t off = (size_t)gr * 64 + jb * 16 + r15;
                    float prev = first ? linb[jb * 16 + r15] : logits[off];
                    logits[off] = prev + accj[jb][reg];
                }
            }
        }
    }
}

// h_out[d][:] = relu(dinv[d] * sum_{s in N(d)} bf16m[s][:] + b)
// TWO adjacent nodes per wave (independent gather chains -> 8 loads in flight).
// 4 groups of 16 lanes each gather full 256 B rows (16 B/lane).
// All __shfl in wave-uniform control flow with clamped indices (R3 lesson);
// loads/accumulates are exec-predicated (safe).
__global__ __launch_bounds__(256) void k_agg(const int* __restrict__ rowptr,
                                             const int* __restrict__ csr,
                                             const uint4* __restrict__ m4,
                                             const float* __restrict__ dinv,
                                             const float* __restrict__ bias,
                                             float* __restrict__ out) {
    int w = threadIdx.x >> 6, lane = threadIdx.x & 63;
    int grp = lane >> 4, lj = lane & 15;
    int nodeA = (blockIdx.x * 4 + w) * 2;       // grid 12500*4*2 = 100000 exact
    int nodeB = nodeA + 1;
    int begA = rowptr[nodeA], begB = rowptr[nodeB], endB = rowptr[nodeB + 1];
    int endA = begB;

    float a[8], b8[8];
#pragma unroll
    for (int q = 0; q < 8; ++q) { a[q] = 0.f; b8[q] = 0.f; }

    auto accA = [&](uint4 v) {
        a[0] += __uint_as_float(v.x << 16);
        a[1] += __uint_as_float(v.x & 0xffff0000u);
        a[2] += __uint_as_float(v.y << 16);
        a[3] += __uint_as_float(v.y & 0xffff0000u);
        a[4] += __uint_as_float(v.z << 16);
        a[5] += __uint_as_float(v.z & 0xffff0000u);
        a[6] += __uint_as_float(v.w << 16);
        a[7] += __uint_as_float(v.w & 0xffff0000u);
    };
    auto accB = [&](uint4 v) {
        b8[0] += __uint_as_float(v.x << 16);
        b8[1] += __uint_as_float(v.x & 0xffff0000u);
        b8[2] += __uint_as_float(v.y << 16);
        b8[3] += __uint_as_float(v.y & 0xffff0000u);
        b8[4] += __uint_as_float(v.z << 16);
        b8[5] += __uint_as_float(v.z & 0xffff0000u);
        b8[6] += __uint_as_float(v.w << 16);
        b8[7] += __uint_as_float(v.w & 0xffff0000u);
    };

    int curA = begA, curB = begB;
    while (curA < endA || curB < endB) {        // wave-uniform
        int cntA = min(64, endA - curA);        // may be <=0 when A done
        int cntB = min(64, endB - curB);
        if (cntA < 0) cntA = 0;
        if (cntB < 0) cntB = 0;
        int svA = (lane < cntA) ? csr[curA + lane] : 0;
        int svB = (lane < cntB) ? csr[curB + lane] : 0;
        int kmax = max(cntA, cntB);
        int cA = max(cntA - 1, 0), cB = max(cntB - 1, 0);
        for (int k = 0; k < kmax; k += 8) {     // wave-uniform trip count
            // all shfls executed by every lane, indices clamped in-range
            int sA0 = __shfl(svA, min(k + grp, cA));
            int sA1 = __shfl(svA, min(k + 4 + grp, cA));
            int sB0 = __shfl(svB, min(k + grp, cB));
            int sB1 = __shfl(svB, min(k + 4 + grp, cB));
            if (k + grp < cntA)     accA(m4[(size_t)sA0 * 16 + lj]);
            if (k + 4 + grp < cntA) accA(m4[(size_t)sA1 * 16 + lj]);
            if (k + grp < cntB)     accB(m4[(size_t)sB0 * 16 + lj]);
            if (k + 4 + grp < cntB) accB(m4[(size_t)sB1 * 16 + lj]);
        }
        curA += cntA; curB += cntB;
    }
#pragma unroll
    for (int q = 0; q < 8; ++q) {
        a[q] += __shfl_xor(a[q], 16);
        b8[q] += __shfl_xor(b8[q], 16);
    }
#pragma unroll
    for (int q = 0; q < 8; ++q) {
        a[q] += __shfl_xor(a[q], 32);
        b8[q] += __shfl_xor(b8[q], 32);
    }

    float scA = dinv[nodeA], scB = dinv[nodeB];
    if (grp == 0) {
        float4 bb = ((const float4*)bias)[lj * 2];
        float4 o = make_float4(fmaxf(a[0] * scA + bb.x, 0.f),
                               fmaxf(a[1] * scA + bb.y, 0.f),
                               fmaxf(a[2] * scA + bb.z, 0.f),
                               fmaxf(a[3] * scA + bb.w, 0.f));
        *(float4*)&out[(size_t)nodeA * 128 + lj * 8] = o;
    } else if (grp == 1) {
        float4 bb = ((const float4*)bias)[lj * 2 + 1];
        float4 o = make_float4(fmaxf(a[4] * scA + bb.x, 0.f),
                               fmaxf(a[5] * scA + bb.y, 0.f),
                               fmaxf(a[6] * scA + bb.z, 0.f),
                               fmaxf(a[7] * scA + bb.w, 0.f));
        *(float4*)&out[(size_t)nodeA * 128 + lj * 8 + 4] = o;
    } else if (grp == 2) {
        float4 bb = ((const float4*)bias)[lj * 2];
        float4 o = make_float4(fmaxf(b8[0] * scB + bb.x, 0.f),
                               fmaxf(b8[1] * scB + bb.y, 0.f),
                               fmaxf(b8[2] * scB + bb.z, 0.f),
                               fmaxf(b8[3] * scB + bb.w, 0.f));
        *(float4*)&out[(size_t)nodeB * 128 + lj * 8] = o;
    } else {
        float4 bb = ((const float4*)bias)[lj * 2 + 1];
        float4 o = make_float4(fmaxf(b8[4] * scB + bb.x, 0.f),
                               fmaxf(b8[5] * scB + bb.y, 0.f),
                               fmaxf(b8[6] * scB + bb.z, 0.f),
                               fmaxf(b8[7] * scB + bb.w, 0.f));
        *(float4*)&out[(size_t)nodeB * 128 + lj * 8 + 4] = o;
    }
}

// Final: logits[r][:] += H[r][:] @ Wl; then in-place log_softmax (width-16 shfl).
__global__ __launch_bounds__(256) void k_jk_lsm(const float* __restrict__ Hl,
                                                const float* __restrict__ Wl,
                                                float* __restrict__ logits) {
    __shared__ float At[32][68];
    __shared__ float Wt[32][64];
    int tid = threadIdx.x;
    int tx = tid & 15, ty = tid >> 4;
    int row0 = blockIdx.x * 64;
    float acc[4][4];
#pragma unroll
    for (int j = 0; j < 4; ++j)
#pragma unroll
        for (int c = 0; c < 4; ++c) acc[j][c] = 0.f;

    for (int kb = 0; kb < 128; kb += 32) {
#pragma unroll
        for (int i = 0; i < 2; ++i) {
            int kr = ty + i * 16;
            float4 wv = *(const float4*)&Wl[(size_t)(kb + kr) * 64 + tx * 4];
            *(float4*)&Wt[kr][tx * 4] = wv;
        }
#pragma unroll
        for (int i = 0; i < 2; ++i) {
            int idx = tid + i * 256;
            int r = idx >> 3, c4 = idx & 7;
            int gr = row0 + r;
            float4 v = make_float4(0.f, 0.f, 0.f, 0.f);
            if (gr < NN) v = *(const float4*)&Hl[(size_t)gr * 128 + kb + c4 * 4];
            At[c4 * 4 + 0][r] = v.x;
            At[c4 * 4 + 1][r] = v.y;
            At[c4 * 4 + 2][r] = v.z;
            At[c4 * 4 + 3][r] = v.w;
        }
        __syncthreads();
#pragma unroll 4
        for (int k = 0; k < 32; ++k) {
            float4 a4 = *(const float4*)&At[k][ty * 4];
            float4 wv = *(const float4*)&Wt[k][tx * 4];
            float a[4] = {a4.x, a4.y, a4.z, a4.w};
#pragma unroll
            for (int j = 0; j < 4; ++j) {
                acc[j][0] += a[j] * wv.x;
                acc[j][1] += a[j] * wv.y;
                acc[j][2] += a[j] * wv.z;
                acc[j][3] += a[j] * wv.w;
            }
        }
        __syncthreads();
    }
#pragma unroll
    for (int j = 0; j < 4; ++j) {
        int r = row0 + ty * 4 + j;
        if (r < NN) {
            float4 prev = *(const float4*)&logits[(size_t)r * 64 + tx * 4];
            float v0 = prev.x + acc[j][0];
            float v1 = prev.y + acc[j][1];
            float v2 = prev.z + acc[j][2];
            float v3 = prev.w + acc[j][3];
            float mx = fmaxf(fmaxf(v0, v1), fmaxf(v2, v3));
#pragma unroll
            for (int s = 1; s < 16; s <<= 1) mx = fmaxf(mx, __shfl_xor(mx, s, 16));
            float e0 = expf(v0 - mx), e1 = expf(v1 - mx);
            float e2 = expf(v2 - mx), e3 = expf(v3 - mx);
            float sum = (e0 + e1) + (e2 + e3);
#pragma unroll
            for (int s = 1; s < 16; s <<= 1) sum += __shfl_xor(sum, s, 16);
            float ls = logf(sum) + mx;
            float4 o = make_float4(v0 - ls, v1 - ls, v2 - ls, v3 - ls);
            *(float4*)&logits[(size_t)r * 64 + tx * 4] = o;
        }
    }
}

// ---------------- launch ----------------

extern "C" void kernel_launch(void* const* d_in, const int* in_sizes, int n_in,
                              void* d_out, int out_size, void* d_ws, size_t ws_size,
                              hipStream_t stream) {
    const float* x    = (const float*)d_in[0];
    const int*   ei   = (const int*)d_in[1];
    const float* W[4] = {(const float*)d_in[2], (const float*)d_in[4],
                         (const float*)d_in[6], (const float*)d_in[8]};
    const float* b[4] = {(const float*)d_in[3], (const float*)d_in[5],
                         (const float*)d_in[7], (const float*)d_in[9]};
    const float* linW = (const float*)d_in[10];
    const float* linb = (const float*)d_in[11];
    float* out = (float*)d_out;

    char* wp = (char*)d_ws;
    auto alloc = [&](size_t bytes) {
        void* p = (void*)wp;
        wp += (bytes + 255) & ~(size_t)255;
        return p;
    };
    int*   flag   = (int*)  alloc(4);
    int*   deg    = (int*)  alloc((size_t)NN * 4);
    float* dinv   = (float*)alloc((size_t)NN * 4);
    int*   rowptr = (int*)  alloc((size_t)(NN + 1) * 4);
    int*   rank   = (int*)  alloc((size_t)NE * 4);
    int*   bsum   = (int*)  alloc(512);
    int*   boff   = (int*)  alloc(512);
    int*   csr    = (int*)  alloc((size_t)NTOT * 4);
    unsigned short* WT  = (unsigned short*)alloc((size_t)4 * 128 * 128 * 2);
    unsigned short* WjT = (unsigned short*)alloc((size_t)4 * 64 * 128 * 2);
    unsigned short* bufM = (unsigned short*)alloc((size_t)NN * 128 * 2);
    float* bufB   = (float*)alloc((size_t)NN * HF * 4);
    float* bufC   = (float*)alloc((size_t)NN * HF * 4);

    dim3 blk(256);
    k_init   <<<391, blk, 0, stream>>>(flag, deg);
    k_prep   <<<384, blk, 0, stream>>>(W[0], W[1], W[2], W[3], linW, WT, WjT);
    k_detect <<<1024, blk, 0, stream>>>(ei, flag);
    k_histr  <<<6250, blk, 0, stream>>>(ei, flag, deg, rank);
    k_scanA  <<<98, blk, 0, stream>>>(deg, rowptr, bsum, dinv);
    k_scanB  <<<1, dim3(128), 0, stream>>>(bsum, boff, rowptr);
    k_scanC  <<<391, blk, 0, stream>>>(rowptr, boff);
    k_scat2  <<<6656, blk, 0, stream>>>(ei, flag, rank, rowptr, csr);

    const float* lin[4]  = {x, bufB, bufC, bufB};
    float*       lout[4] = {bufB, bufC, bufB, bufC};
    for (int l = 0; l < 4; ++l) {
        const unsigned short* wjt = (l == 0) ? nullptr : WjT + (size_t)(l - 1) * 64 * 128;
        k_mmf<<<1563, blk, 0, stream>>>(lin[l], WT + (size_t)l * 128 * 128, dinv,
                                        wjt, linb, out, l == 1 ? 1 : 0, bufM);
        k_agg<<<12500, blk, 0, stream>>>(rowptr, csr, (const uint4*)bufM, dinv,
                                         b[l], lout[l]);
    }
    k_jk_lsm<<<1563, blk, 0, stream>>>(lout[3], linW + (size_t)3 * 128 * 64, out);
}

// Round 10
// 586.250 us; speedup vs baseline: 1.0574x; 1.0574x over previous
//
#include <hip/hip_runtime.h>
#include <cstdint>
#include <cstddef>

#define NN 100000
#define NE 1600000
#define NTOT (NE + NN)      // 1700000 edges incl self-loops
#define HF 128
#define OF 64
#define SHARD 12500         // NN/8 dst-range per XCD
#define EPB 1924            // edges per chunk: 832*1924 >= NE
#define NPB 16              // shard nodes per chunk: 832*16 >= SHARD

typedef short bfrag_t __attribute__((ext_vector_type(8)));   // 8 bf16 = 4 VGPR
typedef float f4v     __attribute__((ext_vector_type(4)));   // MFMA acc

// ---------------- helpers ----------------

__device__ __forceinline__ unsigned int f2bf_rne(float f) {
    unsigned int u = __float_as_uint(f);
    return (u + 0x7fffu + ((u >> 16) & 1u)) >> 16;
}
__device__ __forceinline__ unsigned int pack_bf2(float lo, float hi) {
    return f2bf_rne(lo) | (f2bf_rne(hi) << 16);
}

// ---------------- graph preprocessing ----------------

__global__ __launch_bounds__(256) void k_init(int* flag, int* deg) {
    int i = blockIdx.x * 256 + threadIdx.x;
    if (i == 0) *flag = 0;
    if (i < NN) deg[i] = 1;   // self-loop
}

// OR-reduce odd 32-bit words of edge_index: all zero <=> data is int64.
__global__ __launch_bounds__(256) void k_detect(const int* ei, int* flag) {
    int t = blockIdx.x * blockDim.x + threadIdx.x;
    int v = 0;
    for (int i = t; i < NE; i += gridDim.x * blockDim.x) v |= ei[2 * i + 1];
    unsigned long long b = __ballot(v != 0);
    if ((threadIdx.x & 63) == 0 && b) atomicOr(flag, 1);
}

__device__ __forceinline__ int edge_src(const int* ei, int e, bool is64) {
    return is64 ? ei[2 * e] : ei[e];
}
__device__ __forceinline__ int edge_dst(const int* ei, int e, bool is64) {
    return is64 ? ei[2 * (NE + e)] : ei[NE + e];
}

// XCD-sharded histogram: block b -> shard x=b%8; only dst in own shard get
// atomics -> each deg line is touched by ONE XCD -> local-L2 atomics.
__global__ __launch_bounds__(256) void k_hist8(const int* __restrict__ ei,
                                               const int* __restrict__ flag,
                                               int* __restrict__ deg) {
    int x = blockIdx.x & 7, c = blockIdx.x >> 3;
    bool is64 = (*flag) == 0;
    int d0 = x * SHARD;
    int ebeg = c * EPB;
    int eend = min(NE, ebeg + EPB);
    for (int e = ebeg + (int)threadIdx.x; e < eend; e += 256) {
        int d = edge_dst(ei, e, is64);
        if ((unsigned)(d - d0) < SHARD) atomicAdd(&deg[d], 1);
    }
}

// exclusive scan of deg[N] -> rowptr (partial), also dinv = rsqrt(deg)
__global__ __launch_bounds__(256) void k_scanA(const int* deg, int* rowptr, int* bsum,
                                               float* dinv) {
    __shared__ int sh[256];
    int tid = threadIdx.x;
    int base = blockIdx.x * 1024 + tid * 4;
    int v0 = 0, v1 = 0, v2 = 0, v3 = 0;
    if (base + 0 < NN) v0 = deg[base + 0];
    if (base + 1 < NN) v1 = deg[base + 1];
    if (base + 2 < NN) v2 = deg[base + 2];
    if (base + 3 < NN) v3 = deg[base + 3];
    if (base + 0 < NN) dinv[base + 0] = rsqrtf((float)v0);
    if (base + 1 < NN) dinv[base + 1] = rsqrtf((float)v1);
    if (base + 2 < NN) dinv[base + 2] = rsqrtf((float)v2);
    if (base + 3 < NN) dinv[base + 3] = rsqrtf((float)v3);
    int s = v0 + v1 + v2 + v3;
    sh[tid] = s;
    __syncthreads();
    for (int off = 1; off < 256; off <<= 1) {
        int t = (tid >= off) ? sh[tid - off] : 0;
        __syncthreads();
        sh[tid] += t;
        __syncthreads();
    }
    int run = sh[tid] - s;
    if (base + 0 < NN) rowptr[base + 0] = run; run += v0;
    if (base + 1 < NN) rowptr[base + 1] = run; run += v1;
    if (base + 2 < NN) rowptr[base + 2] = run; run += v2;
    if (base + 3 < NN) rowptr[base + 3] = run;
    if (tid == 255) bsum[blockIdx.x] = sh[255];
}

__global__ __launch_bounds__(128) void k_scanB(const int* bsum, int* boff, int* rowptr) {
    __shared__ int sh[128];
    int tid = threadIdx.x;
    int v = (tid < 98) ? bsum[tid] : 0;
    sh[tid] = v;
    __syncthreads();
    for (int off = 1; off < 128; off <<= 1) {
        int t = (tid >= off) ? sh[tid - off] : 0;
        __syncthreads();
        sh[tid] += t;
        __syncthreads();
    }
    if (tid < 98) boff[tid] = sh[tid] - v;
    if (tid == 0) rowptr[NN] = NTOT;
}

__global__ __launch_bounds__(256) void k_scanC(int* rowptr, const int* boff, int* cursor) {
    int i = blockIdx.x * 256 + threadIdx.x;
    if (i < NN) {
        int r = rowptr[i] + boff[i >> 10];
        rowptr[i] = r;
        cursor[i] = r + 1;   // slot r is reserved for the self-loop
    }
}

// XCD-sharded CSR fill with shard-local atomic cursor (one XCD per dst shard
// -> cursor lines stay in local L2).
__global__ __launch_bounds__(256) void k_scat3(const int* __restrict__ ei,
                                               const int* __restrict__ flag,
                                               int* __restrict__ cursor,
                                               const int* __restrict__ rowptr,
                                               int* __restrict__ csr) {
    int x = blockIdx.x & 7, c = blockIdx.x >> 3;
    bool is64 = (*flag) == 0;
    int d0 = x * SHARD;
    int nbeg = d0 + c * NPB;
    int nend = min(d0 + SHARD, nbeg + NPB);
    for (int nd = nbeg + (int)threadIdx.x; nd < nend; nd += 256)
        csr[rowptr[nd]] = nd;                       // self-loop slot
    int ebeg = c * EPB;
    int eend = min(NE, ebeg + EPB);
    for (int e = ebeg + (int)threadIdx.x; e < eend; e += 256) {
        int d = edge_dst(ei, e, is64);
        if ((unsigned)(d - d0) < SHARD) {
            int s = edge_src(ei, e, is64);
            int pos = atomicAdd(&cursor[d], 1);
            csr[pos] = s;
        }
    }
}

// ---------------- x f32 -> bf16 ----------------
__global__ __launch_bounds__(256) void k_xcvt(const float* __restrict__ x,
                                              unsigned int* __restrict__ xb4) {
    int i = blockIdx.x * 256 + threadIdx.x;      // one uint4 (8 bf16) per thread
    if (i >= NN * 16) return;
    float4 v0 = ((const float4*)x)[(size_t)i * 2];
    float4 v1 = ((const float4*)x)[(size_t)i * 2 + 1];
    uint4 o;
    o.x = pack_bf2(v0.x, v0.y);
    o.y = pack_bf2(v0.z, v0.w);
    o.z = pack_bf2(v1.x, v1.y);
    o.w = pack_bf2(v1.z, v1.w);
    ((uint4*)xb4)[i] = o;
}

// ---------------- weight prep: bf16 + transpose to [n][k] ----------------
__global__ __launch_bounds__(256) void k_prep(const float* __restrict__ W0,
                                              const float* __restrict__ W1,
                                              const float* __restrict__ W2,
                                              const float* __restrict__ W3,
                                              const float* __restrict__ linW,
                                              unsigned short* __restrict__ WT,
                                              unsigned short* __restrict__ WjT) {
    int idx = blockIdx.x * 256 + threadIdx.x;
    if (idx < 4 * 128 * 128) {
        int l = idx >> 14, r = idx & 16383, n = r >> 7, k = r & 127;
        const float* Wl = (l == 0) ? W0 : (l == 1) ? W1 : (l == 2) ? W2 : W3;
        WT[idx] = (unsigned short)f2bf_rne(Wl[k * 128 + n]);
    } else if (idx < 4 * 128 * 128 + 4 * 64 * 128) {
        int i2 = idx - 65536;
        int l = i2 >> 13, r = i2 & 8191, n = r >> 7, k = r & 127;
        WjT[i2] = (unsigned short)f2bf_rne(linW[(size_t)(l * 128 + k) * 64 + n]);
    }
}

// ---------------- MFMA matmul + fused JK ----------------
// A is bf16 [N][128]; A fragments are loaded DIRECTLY from global (the MFMA
// A-fragment is a contiguous 16 B per lane: row*256B + ks*64B + q*16B), so no
// A-LDS stage and only one barrier (after W staging).
__global__ __launch_bounds__(256) void k_mmf(const unsigned short* __restrict__ A,
                                             const unsigned short* __restrict__ WT,
                                             const float* __restrict__ dinv,
                                             const unsigned short* __restrict__ WjT,
                                             const float* __restrict__ linb,
                                             float* __restrict__ logits, int first,
                                             unsigned short* __restrict__ m16) {
    __shared__ unsigned short Wlds[128 * 128];   // 32 KB
    __shared__ unsigned short Wjlds[64 * 128];   // 16 KB
    int tid = threadIdx.x;
    int row0 = blockIdx.x * 64;
    bool has_jk = (WjT != nullptr);

    for (int c = tid; c < 2048; c += 256) {       // W^T, swizzled
        int row = c >> 4, c16 = c & 15;
        uint4 v = *(const uint4*)&WT[row * 128 + c16 * 8];
        *(uint4*)((char*)Wlds + row * 256 + ((c16 * 16) ^ ((row & 7) << 4))) = v;
    }
    if (has_jk) {
        for (int c = tid; c < 1024; c += 256) {
            int row = c >> 4, c16 = c & 15;
            uint4 v = *(const uint4*)&WjT[row * 128 + c16 * 8];
            *(uint4*)((char*)Wjlds + row * 256 + ((c16 * 16) ^ ((row & 7) << 4))) = v;
        }
    }

    int lane = tid & 63, w = tid >> 6;
    int r15 = lane & 15, q = lane >> 4;
    int xo = (r15 & 7) << 4;

    // A fragments direct from global (issued before the barrier to overlap)
    int arow = row0 + 16 * w + r15;
    bool av = arow < NN;
    bfrag_t afr[4];
#pragma unroll
    for (int ks = 0; ks < 4; ++ks) {
        bfrag_t z = {0, 0, 0, 0, 0, 0, 0, 0};
        afr[ks] = av ? *(const bfrag_t*)&A[(size_t)arow * 128 + ks * 32 + q * 8] : z;
    }
    __syncthreads();

    f4v acc[8], accj[4];
#pragma unroll
    for (int i = 0; i < 8; ++i) acc[i] = (f4v){0.f, 0.f, 0.f, 0.f};
#pragma unroll
    for (int i = 0; i < 4; ++i) accj[i] = (f4v){0.f, 0.f, 0.f, 0.f};

#pragma unroll
    for (int ks = 0; ks < 4; ++ks) {
        int ko = ks * 64 + q * 16;
        bfrag_t a = afr[ks];
#pragma unroll
        for (int nb = 0; nb < 8; ++nb) {
            bfrag_t b = *(const bfrag_t*)((const char*)Wlds + (nb * 16 + r15) * 256 + (ko ^ xo));
            acc[nb] = __builtin_amdgcn_mfma_f32_16x16x32_bf16(a, b, acc[nb], 0, 0, 0);
        }
        if (has_jk) {
#pragma unroll
            for (int jb = 0; jb < 4; ++jb) {
                bfrag_t b = *(const bfrag_t*)((const char*)Wjlds + (jb * 16 + r15) * 256 + (ko ^ xo));
                accj[jb] = __builtin_amdgcn_mfma_f32_16x16x32_bf16(a, b, accj[jb], 0, 0, 0);
            }
        }
    }

#pragma unroll
    for (int reg = 0; reg < 4; ++reg) {
        int gr = row0 + 16 * w + q * 4 + reg;
        if (gr < NN) {
            float sc = dinv[gr];
#pragma unroll
            for (int nb = 0; nb < 8; ++nb)
                m16[(size_t)gr * 128 + nb * 16 + r15] =
                    (unsigned short)f2bf_rne(acc[nb][reg] * sc);
            if (has_jk) {
#pragma unroll
                for (int jb = 0; jb < 4; ++jb) {
                    size_t off = (size_t)gr * 64 + jb * 16 + r15;
                    float prev = first ? linb[jb * 16 + r15] : logits[off];
                    logits[off] = prev + accj[jb][reg];
                }
            }
        }
    }
}

// h_out[d][:] = bf16(relu(dinv[d] * sum_{s in N(d)} bf16m[s][:] + b))
// one wave per node (R8 structure); 4 groups of 16 lanes gather full 256 B
// rows (16 B/lane); 16-edge inner step = 4 independent gathers in flight.
// All __shfl executed by ALL lanes (wave-uniform); grp0 writes the full
// 256 B bf16 output row (one uint4 per lane).
__global__ __launch_bounds__(256) void k_agg(const int* __restrict__ rowptr,
                                             const int* __restrict__ csr,
                                             const uint4* __restrict__ m4,
                                             const float* __restrict__ dinv,
                                             const float* __restrict__ bias,
                                             unsigned short* __restrict__ outb) {
    int w = threadIdx.x >> 6, lane = threadIdx.x & 63;
    int grp = lane >> 4, lj = lane & 15;
    int node = blockIdx.x * 4 + w;
    if (node >= NN) return;
    int beg = rowptr[node], end = rowptr[node + 1];

    float a[8];
#pragma unroll
    for (int q = 0; q < 8; ++q) a[q] = 0.f;

    auto acc8 = [&](uint4 v) {
        a[0] += __uint_as_float(v.x << 16);
        a[1] += __uint_as_float(v.x & 0xffff0000u);
        a[2] += __uint_as_float(v.y << 16);
        a[3] += __uint_as_float(v.y & 0xffff0000u);
        a[4] += __uint_as_float(v.z << 16);
        a[5] += __uint_as_float(v.z & 0xffff0000u);
        a[6] += __uint_as_float(v.w << 16);
        a[7] += __uint_as_float(v.w & 0xffff0000u);
    };

    for (int base = beg; base < end; base += 64) {
        int cnt = min(64, end - base);
        int sv = (lane < cnt) ? csr[base + lane] : 0;
        int k = 0;
        for (; k + 16 <= cnt; k += 16) {
            int s0 = __shfl(sv, k + grp);
            int s1 = __shfl(sv, k + 4 + grp);
            int s2 = __shfl(sv, k + 8 + grp);
            int s3 = __shfl(sv, k + 12 + grp);
            uint4 v0 = m4[(size_t)s0 * 16 + lj];
            uint4 v1 = m4[(size_t)s1 * 16 + lj];
            uint4 v2 = m4[(size_t)s2 * 16 + lj];
            uint4 v3 = m4[(size_t)s3 * 16 + lj];
            acc8(v0); acc8(v1); acc8(v2); acc8(v3);
        }
        for (; k + 4 <= cnt; k += 4) {      // wave-uniform
            int s = __shfl(sv, k + grp);
            uint4 v = m4[(size_t)s * 16 + lj];
            acc8(v);
        }
        int rem = cnt - k;                  // 0..3
        if (rem) {                          // wave-uniform
            int idx = k + grp;
            if (idx >= cnt) idx = cnt - 1;  // clamp; shuffle by ALL lanes
            int s = __shfl(sv, idx);
            if (grp < rem) {                // only accumulate predicated
                uint4 v = m4[(size_t)s * 16 + lj];
                acc8(v);
            }
        }
    }
#pragma unroll
    for (int q = 0; q < 8; ++q) a[q] += __shfl_xor(a[q], 16);
#pragma unroll
    for (int q = 0; q < 8; ++q) a[q] += __shfl_xor(a[q], 32);

    if (grp == 0) {
        float sc = dinv[node];
        float4 b0 = ((const float4*)bias)[lj * 2];
        float4 b1 = ((const float4*)bias)[lj * 2 + 1];
        float r0 = fmaxf(a[0] * sc + b0.x, 0.f);
        float r1 = fmaxf(a[1] * sc + b0.y, 0.f);
        float r2 = fmaxf(a[2] * sc + b0.z, 0.f);
        float r3 = fmaxf(a[3] * sc + b0.w, 0.f);
        float r4 = fmaxf(a[4] * sc + b1.x, 0.f);
        float r5 = fmaxf(a[5] * sc + b1.y, 0.f);
        float r6 = fmaxf(a[6] * sc + b1.z, 0.f);
        float r7 = fmaxf(a[7] * sc + b1.w, 0.f);
        uint4 o;
        o.x = pack_bf2(r0, r1);
        o.y = pack_bf2(r2, r3);
        o.z = pack_bf2(r4, r5);
        o.w = pack_bf2(r6, r7);
        *(uint4*)&outb[(size_t)node * 128 + lj * 8] = o;
    }
}

// Final: logits[r][:] += Hl(bf16)[r][:] @ Wl; then in-place log_softmax.
__global__ __launch_bounds__(256) void k_jk_lsm(const unsigned short* __restrict__ Hl,
                                                const float* __restrict__ Wl,
                                                float* __restrict__ logits) {
    __shared__ float At[32][68];
    __shared__ float Wt[32][64];
    int tid = threadIdx.x;
    int tx = tid & 15, ty = tid >> 4;
    int row0 = blockIdx.x * 64;
    float acc[4][4];
#pragma unroll
    for (int j = 0; j < 4; ++j)
#pragma unroll
        for (int c = 0; c < 4; ++c) acc[j][c] = 0.f;

    for (int kb = 0; kb < 128; kb += 32) {
#pragma unroll
        for (int i = 0; i < 2; ++i) {                 // Wl chunk 32x64
            int kr = ty + i * 16;
            float4 wv = *(const float4*)&Wl[(size_t)(kb + kr) * 64 + tx * 4];
            *(float4*)&Wt[kr][tx * 4] = wv;
        }
        {   // A chunk 64x32 from bf16, transposed store
            int r = tid >> 2, c8 = tid & 3;
            int gr = row0 + r;
            uint4 v = make_uint4(0, 0, 0, 0);
            if (gr < NN) v = *(const uint4*)&Hl[(size_t)gr * 128 + kb + c8 * 8];
            At[c8 * 8 + 0][r] = __uint_as_float(v.x << 16);
            At[c8 * 8 + 1][r] = __uint_as_float(v.x & 0xffff0000u);
            At[c8 * 8 + 2][r] = __uint_as_float(v.y << 16);
            At[c8 * 8 + 3][r] = __uint_as_float(v.y & 0xffff0000u);
            At[c8 * 8 + 4][r] = __uint_as_float(v.z << 16);
            At[c8 * 8 + 5][r] = __uint_as_float(v.z & 0xffff0000u);
            At[c8 * 8 + 6][r] = __uint_as_float(v.w << 16);
            At[c8 * 8 + 7][r] = __uint_as_float(v.w & 0xffff0000u);
        }
        __syncthreads();
#pragma unroll 4
        for (int k = 0; k < 32; ++k) {
            float4 a4 = *(const float4*)&At[k][ty * 4];
            float4 wv = *(const float4*)&Wt[k][tx * 4];
            float a[4] = {a4.x, a4.y, a4.z, a4.w};
#pragma unroll
            for (int j = 0; j < 4; ++j) {
                acc[j][0] += a[j] * wv.x;
                acc[j][1] += a[j] * wv.y;
                acc[j][2] += a[j] * wv.z;
                acc[j][3] += a[j] * wv.w;
            }
        }
        __syncthreads();
    }
#pragma unroll
    for (int j = 0; j < 4; ++j) {
        int r = row0 + ty * 4 + j;
        if (r < NN) {
            float4 prev = *(const float4*)&logits[(size_t)r * 64 + tx * 4];
            float v0 = prev.x + acc[j][0];
            float v1 = prev.y + acc[j][1];
            float v2 = prev.z + acc[j][2];
            float v3 = prev.w + acc[j][3];
            float mx = fmaxf(fmaxf(v0, v1), fmaxf(v2, v3));
#pragma unroll
            for (int s = 1; s < 16; s <<= 1) mx = fmaxf(mx, __shfl_xor(mx, s, 16));
            float e0 = expf(v0 - mx), e1 = expf(v1 - mx);
            float e2 = expf(v2 - mx), e3 = expf(v3 - mx);
            float sum = (e0 + e1) + (e2 + e3);
#pragma unroll
            for (int s = 1; s < 16; s <<= 1) sum += __shfl_xor(sum, s, 16);
            float ls = logf(sum) + mx;
            float4 o = make_float4(v0 - ls, v1 - ls, v2 - ls, v3 - ls);
            *(float4*)&logits[(size_t)r * 64 + tx * 4] = o;
        }
    }
}

// ---------------- launch ----------------

extern "C" void kernel_launch(void* const* d_in, const int* in_sizes, int n_in,
                              void* d_out, int out_size, void* d_ws, size_t ws_size,
                              hipStream_t stream) {
    const float* x    = (const float*)d_in[0];
    const int*   ei   = (const int*)d_in[1];
    const float* W[4] = {(const float*)d_in[2], (const float*)d_in[4],
                         (const float*)d_in[6], (const float*)d_in[8]};
    const float* b[4] = {(const float*)d_in[3], (const float*)d_in[5],
                         (const float*)d_in[7], (const float*)d_in[9]};
    const float* linW = (const float*)d_in[10];
    const float* linb = (const float*)d_in[11];
    float* out = (float*)d_out;

    char* wp = (char*)d_ws;
    auto alloc = [&](size_t bytes) {
        void* p = (void*)wp;
        wp += (bytes + 255) & ~(size_t)255;
        return p;
    };
    int*   flag   = (int*)  alloc(4);
    int*   deg    = (int*)  alloc((size_t)NN * 4);
    float* dinv   = (float*)alloc((size_t)NN * 4);
    int*   rowptr = (int*)  alloc((size_t)(NN + 1) * 4);
    int*   cursor = (int*)  alloc((size_t)NN * 4);
    int*   bsum   = (int*)  alloc(512);
    int*   boff   = (int*)  alloc(512);
    int*   csr    = (int*)  alloc((size_t)NTOT * 4);
    unsigned short* WT  = (unsigned short*)alloc((size_t)4 * 128 * 128 * 2);
    unsigned short* WjT = (unsigned short*)alloc((size_t)4 * 64 * 128 * 2);
    unsigned short* xb   = (unsigned short*)alloc((size_t)NN * 128 * 2);  // bf16 x
    unsigned short* bufM = (unsigned short*)alloc((size_t)NN * 128 * 2);  // messages
    unsigned short* bufB = (unsigned short*)alloc((size_t)NN * 128 * 2);  // bf16 h
    unsigned short* bufC = (unsigned short*)alloc((size_t)NN * 128 * 2);

    dim3 blk(256);
    k_init   <<<391, blk, 0, stream>>>(flag, deg);
    k_prep   <<<384, blk, 0, stream>>>(W[0], W[1], W[2], W[3], linW, WT, WjT);
    k_detect <<<1024, blk, 0, stream>>>(ei, flag);
    k_xcvt   <<<6250, blk, 0, stream>>>(x, (unsigned int*)xb);
    k_hist8  <<<6656, blk, 0, stream>>>(ei, flag, deg);
    k_scanA  <<<98, blk, 0, stream>>>(deg, rowptr, bsum, dinv);
    k_scanB  <<<1, dim3(128), 0, stream>>>(bsum, boff, rowptr);
    k_scanC  <<<391, blk, 0, stream>>>(rowptr, boff, cursor);
    k_scat3  <<<6656, blk, 0, stream>>>(ei, flag, cursor, rowptr, csr);

    const unsigned short* lin[4] = {xb, bufB, bufC, bufB};
    unsigned short*      lout[4] = {bufB, bufC, bufB, bufC};
    for (int l = 0; l < 4; ++l) {
        const unsigned short* wjt = (l == 0) ? nullptr : WjT + (size_t)(l - 1) * 64 * 128;
        k_mmf<<<1563, blk, 0, stream>>>(lin[l], WT + (size_t)l * 128 * 128, dinv,
                                        wjt, linb, out, l == 1 ? 1 : 0, bufM);
        k_agg<<<25000, blk, 0, stream>>>(rowptr, csr, (const uint4*)bufM, dinv,
                                         b[l], lout[l]);
    }
    k_jk_lsm<<<1563, blk, 0, stream>>>(lout[3], linW + (size_t)3 * 128 * 64, out);
}